// Round 8
// baseline (451.766 us; speedup 1.0000x reference)
//
#include <hip/hip_runtime.h>
#include <hip/hip_bf16.h>
#include <cmath>

#define NN 2048
#define DIN 768
#define DHID 1024
#define NHEADS 8
#define FPRIME 128
#define DFFN 2048
#define SEN_LIM 2042
#define MAXDEG 256

using short8 = __attribute__((ext_vector_type(8))) short;
using f32x4  = __attribute__((ext_vector_type(4))) float;

#if defined(__has_builtin)
#  if __has_builtin(__builtin_amdgcn_global_load_lds)
#    define HAVE_GLL 1
#  endif
#endif
#ifndef HAVE_GLL
#  define HAVE_GLL 0
#endif

__device__ inline unsigned short f2bf(float f) {
    unsigned u = __float_as_uint(f);
    unsigned r = u + 0x7FFFu + ((u >> 16) & 1u);   // RNE
    return (unsigned short)(r >> 16);
}
__device__ inline float bf2f(unsigned short h) {
    return __uint_as_float(((unsigned)h) << 16);
}
__device__ inline void store_out(float* p, float v) { *p = v; }
__device__ inline void store_out(unsigned short* p, float v) { *p = f2bf(v); }

#if HAVE_GLL
__device__ inline void gll16(const unsigned short* g, unsigned short* l) {
    __builtin_amdgcn_global_load_lds(
        (const __attribute__((address_space(1))) unsigned int*)g,
        (__attribute__((address_space(3))) unsigned int*)l, 16, 0, 0);
}
#endif

template<int S> __device__ inline void wait_vmcnt() {
    if constexpr (S == 0)      asm volatile("s_waitcnt vmcnt(0)" ::: "memory");
    else if constexpr (S == 4) asm volatile("s_waitcnt vmcnt(4)" ::: "memory");
    else if constexpr (S == 6) asm volatile("s_waitcnt vmcnt(6)" ::: "memory");
    else                       asm volatile("s_waitcnt vmcnt(8)" ::: "memory");
}

// ---------------------------------------------------------------------------
// Neighbor lists
// ---------------------------------------------------------------------------
__global__ __launch_bounds__(256) void build_nbrs(
    const float* __restrict__ adj,
    unsigned short* __restrict__ sen_idx, int* __restrict__ sen_cnt,
    unsigned short* __restrict__ sec_idx, int* __restrict__ sec_cnt)
{
    const int i = blockIdx.x;
    __shared__ int c_sen, c_sec;
    if (threadIdx.x == 0) { c_sen = 0; c_sec = 0; }
    __syncthreads();
    for (int j4 = threadIdx.x; j4 < NN / 4; j4 += 256) {
        float4 v = *(const float4*)&adj[(size_t)i * NN + j4 * 4];
        float vs[4] = {v.x, v.y, v.z, v.w};
        #pragma unroll
        for (int q = 0; q < 4; ++q) {
            if (vs[q] != 0.0f) {
                int j = j4 * 4 + q;
                if (j < SEN_LIM) {
                    int p = atomicAdd(&c_sen, 1);
                    if (p < MAXDEG) sen_idx[(size_t)i * MAXDEG + p] = (unsigned short)j;
                } else {
                    int p = atomicAdd(&c_sec, 1);
                    if (p < 8) sec_idx[i * 8 + p] = (unsigned short)j;
                }
            }
        }
    }
    __syncthreads();
    if (threadIdx.x == 0) { sen_cnt[i] = min(c_sen, MAXDEG); sec_cnt[i] = min(c_sec, 8); }
}

// ---------------------------------------------------------------------------
// Mega transpose/cast
// ---------------------------------------------------------------------------
struct TPJob { const float* s; unsigned short* d; int K, N, start, trans; };
struct TPJobs { TPJob j[11]; };

__global__ __launch_bounds__(256) void mega_tp(TPJobs jobs, int njobs)
{
    __shared__ float t[32][33];
    const int tile = blockIdx.x;
    int ji = 0;
    for (int k = 1; k < 11; ++k)
        if (k < njobs && tile >= jobs.j[k].start) ji = k;
    const TPJob jb = jobs.j[ji];
    const int lt = tile - jb.start;
    const int ntx = jb.N >> 5;
    const int bn = (lt % ntx) * 32, bk = (lt / ntx) * 32;
    const int tx = threadIdx.x & 31, ty = threadIdx.x >> 5;
    if (jb.trans) {
        #pragma unroll
        for (int r = 0; r < 4; ++r)
            t[ty + r * 8][tx] = jb.s[(size_t)(bk + ty + r * 8) * jb.N + bn + tx];
        __syncthreads();
        #pragma unroll
        for (int r = 0; r < 4; ++r) {
            int n = ty + r * 8;
            jb.d[(size_t)(bn + n) * jb.K + bk + tx] = f2bf(t[tx][n]);
        }
    } else {
        #pragma unroll
        for (int r = 0; r < 4; ++r) {
            size_t e = (size_t)(bk + ty + r * 8) * jb.N + bn + tx;
            jb.d[e] = f2bf(jb.s[e]);
        }
    }
}

// ---------------------------------------------------------------------------
// bf16 MFMA GEMM: XOR-swizzled LDS + double-buffered 2-phase pipeline.
// Optional dual problem via blockIdx.z.
// ---------------------------------------------------------------------------
template<int BM, int BN, typename OUT_T>
__global__ __launch_bounds__(256) void gemm_mfma(
    const unsigned short* __restrict__ A0, const unsigned short* __restrict__ A1,
    const unsigned short* __restrict__ BT0, const unsigned short* __restrict__ BT1,
    const float* __restrict__ bias, const float* __restrict__ resid,
    OUT_T* __restrict__ C0, OUT_T* __restrict__ C1,
    unsigned short* __restrict__ Cb0, unsigned short* __restrict__ Cb1,
    int M, int N, int K, int act)
{
    constexpr int BK = 64;
    constexpr int WR = BM / 64;
    constexpr int WC = 4 / WR;
    constexpr int NF = BN / (WC * 16);
    constexpr int ACH = BM / 32;
    constexpr int BCH = BN / 32;
    constexpr int S = ACH + BCH;
    __shared__ unsigned short Asm[2][BM * BK];
    __shared__ unsigned short Bsm[2][BN * BK];
    const int z = blockIdx.z;
    const unsigned short* A  = z ? A1  : A0;
    const unsigned short* BT = z ? BT1 : BT0;
    OUT_T* C = z ? C1 : C0;
    unsigned short* Cb = z ? Cb1 : Cb0;
    const int tid = threadIdx.x;
    const int lane = tid & 63, w = tid >> 6;
    const int wr = w / WC, wc = w % WC;
    const int bm = blockIdx.y * BM, bn = blockIdx.x * BN;

    f32x4 acc[4][NF];
    #pragma unroll
    for (int mi = 0; mi < 4; ++mi)
        #pragma unroll
        for (int ni = 0; ni < NF; ++ni)
            acc[mi][ni] = (f32x4){0.f, 0.f, 0.f, 0.f};

    const unsigned short* Abase = A + (size_t)bm * K;
    const unsigned short* Bbase = BT + (size_t)bn * K;

    auto stage = [&](int b, int k0) {
        #pragma unroll
        for (int c = 0; c < ACH; ++c) {
            int e = (tid + c * 256) * 8;
            int r = e >> 6, kk = e & 63;
            int kks = kk ^ ((r & 7) << 3);
#if HAVE_GLL
            gll16(&Abase[(size_t)r * K + k0 + kks], &Asm[b][e]);
#else
            *(short8*)&Asm[b][e] = *(const short8*)&Abase[(size_t)r * K + k0 + kks];
#endif
        }
        #pragma unroll
        for (int c = 0; c < BCH; ++c) {
            int e = (tid + c * 256) * 8;
            int r = e >> 6, kk = e & 63;
            int kks = kk ^ ((r & 7) << 3);
#if HAVE_GLL
            gll16(&Bbase[(size_t)r * K + k0 + kks], &Bsm[b][e]);
#else
            *(short8*)&Bsm[b][e] = *(const short8*)&Bbase[(size_t)r * K + k0 + kks];
#endif
        }
    };

    const int nk = K / BK;
    stage(0, 0);
    int buf = 0;
    for (int t = 0; t < nk; ++t) {
        if (t + 1 < nk) {
            stage(buf ^ 1, (t + 1) * BK);
            wait_vmcnt<S>();
        } else {
            wait_vmcnt<0>();
        }
        __builtin_amdgcn_s_barrier();
        #pragma unroll
        for (int ks = 0; ks < 2; ++ks) {
            short8 af[4], bfv[NF];
            #pragma unroll
            for (int mi = 0; mi < 4; ++mi) {
                int row = wr * 64 + mi * 16 + (lane & 15);
                int col = (ks * 32 + (lane >> 4) * 8) ^ ((row & 7) << 3);
                af[mi] = *(const short8*)&Asm[buf][row * 64 + col];
            }
            #pragma unroll
            for (int ni = 0; ni < NF; ++ni) {
                int row = wc * (BN / WC) + ni * 16 + (lane & 15);
                int col = (ks * 32 + (lane >> 4) * 8) ^ ((row & 7) << 3);
                bfv[ni] = *(const short8*)&Bsm[buf][row * 64 + col];
            }
            #pragma unroll
            for (int mi = 0; mi < 4; ++mi)
                #pragma unroll
                for (int ni = 0; ni < NF; ++ni)
                    acc[mi][ni] = __builtin_amdgcn_mfma_f32_16x16x32_bf16(
                        af[mi], bfv[ni], acc[mi][ni], 0, 0, 0);
        }
        __builtin_amdgcn_s_barrier();
        buf ^= 1;
    }

    const int rbase = bm + wr * 64;
    const int cbase = bn + wc * (BN / WC);
    #pragma unroll
    for (int mi = 0; mi < 4; ++mi)
        #pragma unroll
        for (int ni = 0; ni < NF; ++ni)
            #pragma unroll
            for (int r = 0; r < 4; ++r) {
                int grow = rbase + mi * 16 + (lane >> 4) * 4 + r;
                int gcol = cbase + ni * 16 + (lane & 15);
                float v = acc[mi][ni][r];
                if (bias)  v += bias[gcol];
                if (act)   v = (v >= 0.f) ? v : 0.01f * v;
                if (resid) v += resid[(size_t)grow * N + gcol];
                store_out(&C[(size_t)grow * N + gcol], v);
                if (Cb) Cb[(size_t)grow * N + gcol] = f2bf(v);
            }
}

// ---------------------------------------------------------------------------
// Fused gl/gr for both branches (bf16 g input) + gmean zeroing.
// ---------------------------------------------------------------------------
__global__ __launch_bounds__(64) void glgr2(
    const unsigned short* __restrict__ gA, const unsigned short* __restrict__ gB,
    int row_stride, int F, int Hlog2, int nb_per_branch,
    const float* __restrict__ aA, const float* __restrict__ aB,
    float* __restrict__ glA, float* __restrict__ grA,
    float* __restrict__ glB, float* __restrict__ grB,
    float* __restrict__ z, int zblocks)
{
    const int bid = blockIdx.x, lane = threadIdx.x;
    if (bid < zblocks) z[bid * 64 + lane] = 0.f;
    const int br = bid >= nb_per_branch;
    const int b = br ? bid - nb_per_branch : bid;
    const int node = b >> Hlog2, h = b - ((b >> Hlog2) << Hlog2);
    const unsigned short* g = (br ? gB : gA) + (size_t)node * row_stride + h * F;
    const float* a = br ? aB : aA;
    float sl = 0.f, sr = 0.f;
    for (int f = lane; f < F; f += 64) {
        float v = bf2f(g[f]);
        sl += v * a[f];
        sr += v * a[F + f];
    }
    #pragma unroll
    for (int off = 32; off > 0; off >>= 1) {
        sl += __shfl_down(sl, off);
        sr += __shfl_down(sr, off);
    }
    if (lane == 0) {
        (br ? glB : glA)[b] = sl;
        (br ? grB : grA)[b] = sr;
    }
}

// col-mean of bf16 matrix; z selects problem. out pre-zeroed (by glgr2).
__global__ __launch_bounds__(256) void col_mean2(
    const unsigned short* __restrict__ g0, const unsigned short* __restrict__ g1,
    int C, float* __restrict__ o0, float* __restrict__ o1)
{
    const unsigned short* g = blockIdx.z ? g1 : g0;
    float* o = blockIdx.z ? o1 : o0;
    int c = blockIdx.x * 256 + threadIdx.x;
    int r0 = blockIdx.y * 128;
    float s = 0.f;
    for (int r = r0; r < r0 + 128; ++r) s += bf2f(g[(size_t)r * C + c]);
    atomicAdd(&o[c], s * (1.0f / 2048.0f));
}

// ---------------------------------------------------------------------------
// Fused sparse GAT attention+aggregation, both branches (grid = 2*NN).
// Score-cache version: scores computed ONCE (pass1 -> LDS, stride 9 pad),
// exp'd in place (pass2), read as weights (pass3, no staging/chunk barriers).
// BT = block threads (256 for HF=1024, 192 for HF=768).
// ---------------------------------------------------------------------------
template<int H, int F, int BT, typename OUT_T>
__global__ __launch_bounds__(BT) void attn_agg2(
    const unsigned short* __restrict__ gb0, const unsigned short* __restrict__ gb1,
    int g_stride,
    const float* __restrict__ gl0, const float* __restrict__ gr0,
    const float* __restrict__ gl1, const float* __restrict__ gr1,
    const unsigned short* __restrict__ idx0, int is0, const int* __restrict__ cnt0,
    const unsigned short* __restrict__ idx1, int is1, const int* __restrict__ cnt1,
    const float* __restrict__ gmean0, const float* __restrict__ gmean1,
    OUT_T* __restrict__ dst0, OUT_T* __restrict__ dst1,
    int dst_stride, int co0, int co1,
    const float* __restrict__ resid, int mode)
{
    constexpr int HF = H * F;
    constexpr int NW = BT / 64;
    constexpr int SR = (H == 8) ? 9 : 1;      // padded score stride (dwords)
    const int bid = blockIdx.x;
    const int br = bid >= NN;
    const int i = br ? bid - NN : bid;
    const unsigned short* gbp = br ? gb1 : gb0;
    const float* gl = br ? gl1 : gl0;
    const float* gr = br ? gr1 : gr0;
    const unsigned short* idx = br ? idx1 : idx0;
    const int is = br ? is1 : is0;
    const int* cnt = br ? cnt1 : cnt0;
    const float* gmean = br ? gmean1 : gmean0;
    OUT_T* dst = br ? dst1 : dst0;
    const int co = br ? co1 : co0;

    const int tid = threadIdx.x;
    const int lane = tid & 63, w = tid >> 6;
    const int n = cnt[i];

    if (n == 0) {
        for (int c = tid; c < HF; c += BT) {
            float v = gmean[c];
            if (mode == 0) v = (v > 0.f) ? v : expm1f(v);
            else           v += resid[(size_t)i * HF + c];
            store_out(&dst[(size_t)i * dst_stride + co + c], v);
        }
        return;
    }

    __shared__ float s_raw[MAXDEG * SR];      // scores -> exp weights
    __shared__ float s_wred[NW * H];
    __shared__ float s_max[H], s_inv[H], s_glh[H];

    if (tid < H) s_glh[tid] = gl[(size_t)i * H + tid];
    __syncthreads();
    float glh[H];
    #pragma unroll
    for (int h = 0; h < H; ++h) glh[h] = s_glh[h];

    const unsigned short* row_idx = idx + (size_t)i * is;

    // Pass 1: compute scores ONCE -> s_raw; track per-head max
    float pmax[H];
    #pragma unroll
    for (int h = 0; h < H; ++h) pmax[h] = -1e30f;
    for (int jj = tid; jj < n; jj += BT) {
        int j = row_idx[jj];
        if (H == 8) {
            float4 ga = *(const float4*)&gr[(size_t)j * 8];
            float4 gbv = *(const float4*)&gr[(size_t)j * 8 + 4];
            float sc[8] = {ga.x, ga.y, ga.z, ga.w, gbv.x, gbv.y, gbv.z, gbv.w};
            #pragma unroll
            for (int h = 0; h < H; ++h) {
                float s = glh[h] + sc[h];
                s = (s >= 0.f) ? s : 0.2f * s;
                s_raw[jj * SR + h] = s;
                pmax[h] = fmaxf(pmax[h], s);
            }
        } else {
            float s = glh[0] + gr[j];
            s = (s >= 0.f) ? s : 0.2f * s;
            s_raw[jj] = s;
            pmax[0] = fmaxf(pmax[0], s);
        }
    }
    #pragma unroll
    for (int h = 0; h < H; ++h)
        #pragma unroll
        for (int off = 32; off > 0; off >>= 1)
            pmax[h] = fmaxf(pmax[h], __shfl_xor(pmax[h], off));
    if (lane == 0)
        #pragma unroll
        for (int h = 0; h < H; ++h) s_wred[w * H + h] = pmax[h];
    __syncthreads();
    if (tid < H) {
        float m = s_wred[tid];
        #pragma unroll
        for (int w2 = 1; w2 < NW; ++w2) m = fmaxf(m, s_wred[w2 * H + tid]);
        s_max[tid] = m;
    }
    __syncthreads();
    float mx[H];
    #pragma unroll
    for (int h = 0; h < H; ++h) mx[h] = s_max[h];

    // Pass 2: exp in place + per-head sum
    float psum[H];
    #pragma unroll
    for (int h = 0; h < H; ++h) psum[h] = 0.f;
    for (int jj = tid; jj < n; jj += BT) {
        #pragma unroll
        for (int h = 0; h < H; ++h) {
            float e = expf(s_raw[jj * SR + h] - mx[h]);
            s_raw[jj * SR + h] = e;
            psum[h] += e;
        }
    }
    #pragma unroll
    for (int h = 0; h < H; ++h)
        #pragma unroll
        for (int off = 32; off > 0; off >>= 1)
            psum[h] += __shfl_xor(psum[h], off);
    if (lane == 0)
        #pragma unroll
        for (int h = 0; h < H; ++h) s_wred[w * H + h] = psum[h];
    __syncthreads();
    if (tid < H) {
        float s = s_wred[tid];
        #pragma unroll
        for (int w2 = 1; w2 < NW; ++w2) s += s_wred[w2 * H + tid];
        s_inv[tid] = 1.f / s;
    }
    __syncthreads();                          // s_raw (exp) + s_inv visible to all

    // Pass 3: gather, weights straight from LDS. Unroll 16 (H=8) / 8 (H=1).
    const int cb = tid * 4;
    const bool active = (cb < HF);
    const int hh = (H == 8) ? (cb >> 7) : 0;
    const float winv = s_inv[hh];
    float a0 = 0.f, a1 = 0.f, a2 = 0.f, a3 = 0.f;

    if (active) {
        constexpr int U = (H == 8) ? 16 : 8;
        int jj = 0;
        for (; jj + U <= n; jj += U) {
            ushort4 v[U]; float wv[U];
            #pragma unroll
            for (int u = 0; u < U; ++u) {
                int j = row_idx[jj + u];
                v[u] = *(const ushort4*)&gbp[(size_t)j * g_stride + cb];
                wv[u] = s_raw[(jj + u) * SR + hh] * winv;
            }
            #pragma unroll
            for (int u = 0; u < U; ++u) {
                a0 += wv[u] * bf2f(v[u].x);
                a1 += wv[u] * bf2f(v[u].y);
                a2 += wv[u] * bf2f(v[u].z);
                a3 += wv[u] * bf2f(v[u].w);
            }
        }
        for (; jj < n; ++jj) {
            int j = row_idx[jj];
            ushort4 v0 = *(const ushort4*)&gbp[(size_t)j * g_stride + cb];
            float w0 = s_raw[jj * SR + hh] * winv;
            a0 += w0 * bf2f(v0.x); a1 += w0 * bf2f(v0.y);
            a2 += w0 * bf2f(v0.z); a3 += w0 * bf2f(v0.w);
        }

        float vv[4] = {a0, a1, a2, a3};
        #pragma unroll
        for (int q = 0; q < 4; ++q) {
            float v = vv[q];
            if (mode == 0) v = (v > 0.f) ? v : expm1f(v);
            else           v += resid[(size_t)i * HF + cb + q];
            store_out(&dst[(size_t)i * dst_stride + co + cb + q], v);
        }
    }
}

// ---------------------------------------------------------------------------
extern "C" void kernel_launch(void* const* d_in, const int* in_sizes, int n_in,
                              void* d_out, int out_size, void* d_ws, size_t ws_size,
                              hipStream_t stream)
{
    const float* feature = (const float*)d_in[0];
    const float* adj     = (const float*)d_in[1];
    const float* g1W1 = (const float*)d_in[2];
    const float* g1a1 = (const float*)d_in[3];
    const float* g1W2 = (const float*)d_in[4];
    const float* g1a2 = (const float*)d_in[5];
    const float* g2W1 = (const float*)d_in[6];
    const float* g2a1 = (const float*)d_in[7];
    const float* g2W2 = (const float*)d_in[8];
    const float* g2a2 = (const float*)d_in[9];
    const float* Wf  = (const float*)d_in[10];
    const float* bfv = (const float*)d_in[11];
    const float* fW1 = (const float*)d_in[12];
    const float* fb1 = (const float*)d_in[13];
    const float* fW2 = (const float*)d_in[14];
    const float* fb2 = (const float*)d_in[15];
    const float* fW3 = (const float*)d_in[16];
    const float* fb3 = (const float*)d_in[17];
    const float* oW1 = (const float*)d_in[18];
    const float* ob1 = (const float*)d_in[19];
    const float* oW2 = (const float*)d_in[20];
    const float* ob2 = (const float*)d_in[21];
    float* out = (float*)d_out;

    char* ws = (char*)d_ws;
    size_t off = 0;
    auto alloc = [&](size_t bytes) -> void* {
        void* p = ws + off;
        off = (off + bytes + 255) & ~(size_t)255;
        return p;
    };
    typedef unsigned short bf_t;
    int* sen_cnt = (int*)alloc((size_t)NN * 4);
    int* sec_cnt = (int*)alloc((size_t)NN * 4);
    unsigned short* sen_idx = (unsigned short*)alloc((size_t)NN * MAXDEG * 2);
    unsigned short* sec_idx = (unsigned short*)alloc((size_t)NN * 8 * 2);
    bf_t*  g1b   = (bf_t*)alloc((size_t)NN * 2048 * 2);
    float* gl1a  = (float*)alloc((size_t)NN * NHEADS * 4);
    float* gr1a  = (float*)alloc((size_t)NN * NHEADS * 4);
    float* gl1b  = (float*)alloc((size_t)NN * NHEADS * 4);
    float* gr1b  = (float*)alloc((size_t)NN * NHEADS * 4);
    bf_t*  x1a   = (bf_t*)alloc((size_t)NN * DHID * 2);
    bf_t*  x1b   = (bf_t*)alloc((size_t)NN * DHID * 2);
    bf_t*  g2aB  = (bf_t*)alloc((size_t)NN * DIN * 2);
    bf_t*  g2bB  = (bf_t*)alloc((size_t)NN * DIN * 2);
    float* gl2a  = (float*)alloc((size_t)NN * 4);
    float* gr2a  = (float*)alloc((size_t)NN * 4);
    float* gl2b  = (float*)alloc((size_t)NN * 4);
    float* gr2b  = (float*)alloc((size_t)NN * 4);
    float* gmeanL1 = (float*)alloc((size_t)2048 * 4);
    float* gmeanL2 = (float*)alloc((size_t)1536 * 4);
    bf_t*  fcat  = (bf_t*)alloc((size_t)NN * (2 * DIN) * 2);
    bf_t*  fbuf  = (bf_t*)alloc((size_t)NN * DIN * 2);
    bf_t*  tA    = (bf_t*)alloc((size_t)NN * DFFN * 2);
    bf_t*  tB    = (bf_t*)alloc((size_t)NN * DFFN * 2);
    bf_t*  featb = (bf_t*)alloc((size_t)NN * DIN * 2);
    bf_t* W1T_AB = (bf_t*)alloc((size_t)2048 * DIN * 2);
    bf_t* g1W2T = (bf_t*)alloc((size_t)DHID * DIN * 2);
    bf_t* g2W2T = (bf_t*)alloc((size_t)DHID * DIN * 2);
    bf_t* WfT   = (bf_t*)alloc((size_t)(2 * DIN) * DIN * 2);
    bf_t* fW1T  = (bf_t*)alloc((size_t)DIN * DFFN * 2);
    bf_t* fW2T  = (bf_t*)alloc((size_t)DFFN * DFFN * 2);
    bf_t* fW3T  = (bf_t*)alloc((size_t)DFFN * DIN * 2);
    bf_t* oW1T  = (bf_t*)alloc((size_t)DIN * DFFN * 2);
    bf_t* oW2T  = (bf_t*)alloc((size_t)DFFN * DIN * 2);

    build_nbrs<<<NN, 256, 0, stream>>>(adj, sen_idx, sen_cnt, sec_idx, sec_cnt);

    TPJobs jobs;
    int cur = 0, nj = 0;
    auto addjob = [&](const float* s, bf_t* d, int K, int N, int trans) {
        jobs.j[nj] = {s, d, K, N, cur, trans};
        cur += (K / 32) * (N / 32);
        ++nj;
    };
    addjob(g1W1, W1T_AB, DIN, DHID, 1);
    addjob(g2W1, W1T_AB + (size_t)1024 * DIN, DIN, DHID, 1);
    addjob(g1W2, g1W2T, DHID, DIN, 1);
    addjob(g2W2, g2W2T, DHID, DIN, 1);
    addjob(Wf, WfT, 2 * DIN, DIN, 1);
    addjob(fW1, fW1T, DIN, DFFN, 1);
    addjob(fW2, fW2T, DFFN, DFFN, 1);
    addjob(fW3, fW3T, DFFN, DIN, 1);
    addjob(oW1, oW1T, DIN, DFFN, 1);
    addjob(oW2, oW2T, DFFN, DIN, 1);
    addjob(feature, featb, NN, DIN, 0);
    mega_tp<<<cur, 256, 0, stream>>>(jobs, nj);

    // Layer-1 GEMM, both branches fused: [2048,768] @ [768,2048] -> g1b bf16
    gemm_mfma<64, 128, bf_t><<<dim3(2048 / 128, NN / 64, 1), 256, 0, stream>>>(
        featb, nullptr, W1T_AB, nullptr, nullptr, nullptr,
        g1b, nullptr, nullptr, nullptr, NN, 2048, DIN, 0);

    glgr2<<<2 * NN * NHEADS, 64, 0, stream>>>(
        g1b, g1b + 1024, 2048, FPRIME, 3, NN * NHEADS,
        g1a1, g2a1, gl1a, gr1a, gl1b, gr1b, gmeanL1, 32);
    col_mean2<<<dim3(2048 / 256, 16, 1), 256, 0, stream>>>(
        g1b, nullptr, 2048, gmeanL1, nullptr);
    attn_agg2<NHEADS, FPRIME, 256, bf_t><<<2 * NN, 256, 0, stream>>>(
        g1b, g1b + 1024, 2048,
        gl1a, gr1a, gl1b, gr1b,
        sen_idx, MAXDEG, sen_cnt, sec_idx, 8, sec_cnt,
        gmeanL1, gmeanL1 + 1024,
        x1a, x1b, DHID, 0, 0, nullptr, 0);

    // Layer-2 dual GEMM: x1{a,b} @ W2{a,b}^T -> g2{a,b} bf16
    gemm_mfma<64, 64, bf_t><<<dim3(DIN / 64, NN / 64, 2), 256, 0, stream>>>(
        x1a, x1b, g1W2T, g2W2T, nullptr, nullptr,
        g2aB, g2bB, nullptr, nullptr, NN, DIN, DHID, 0);

    glgr2<<<2 * NN, 64, 0, stream>>>(
        g2aB, g2bB, DIN, DIN, 0, NN,
        g1a2, g2a2, gl2a, gr2a, gl2b, gr2b, gmeanL2, 24);
    col_mean2<<<dim3(DIN / 256, 16, 2), 256, 0, stream>>>(
        g2aB, g2bB, DIN, gmeanL2, gmeanL2 + DIN);
    attn_agg2<1, DIN, 192, bf_t><<<2 * NN, 192, 0, stream>>>(
        g2aB, g2bB, DIN,
        gl2a, gr2a, gl2b, gr2b,
        sen_idx, MAXDEG, sen_cnt, sec_idx, 8, sec_cnt,
        gmeanL2, gmeanL2 + DIN,
        fcat, fcat, 2 * DIN, DIN, 0, feature, 1);

    // Fusion + MLP chain
    gemm_mfma<64, 64, bf_t><<<dim3(DIN / 64, NN / 64, 1), 256, 0, stream>>>(
        fcat, nullptr, WfT, nullptr, bfv, nullptr,
        fbuf, nullptr, nullptr, nullptr, NN, DIN, 2 * DIN, 1);
    gemm_mfma<64, 128, bf_t><<<dim3(DFFN / 128, NN / 64, 1), 256, 0, stream>>>(
        fbuf, nullptr, fW1T, nullptr, fb1, nullptr,
        tA, nullptr, nullptr, nullptr, NN, DFFN, DIN, 1);
    gemm_mfma<64, 128, bf_t><<<dim3(DFFN / 128, NN / 64, 1), 256, 0, stream>>>(
        tA, nullptr, fW2T, nullptr, fb2, nullptr,
        tB, nullptr, nullptr, nullptr, NN, DFFN, DFFN, 1);
    gemm_mfma<64, 64, bf_t><<<dim3(DIN / 64, NN / 64, 1), 256, 0, stream>>>(
        tB, nullptr, fW3T, nullptr, fb3, nullptr,
        fbuf, nullptr, nullptr, nullptr, NN, DIN, DFFN, 1);
    gemm_mfma<64, 128, bf_t><<<dim3(DFFN / 128, NN / 64, 1), 256, 0, stream>>>(
        fbuf, nullptr, oW1T, nullptr, ob1, nullptr,
        tA, nullptr, nullptr, nullptr, NN, DFFN, DIN, 1);
    gemm_mfma<64, 64, float><<<dim3(DIN / 64, NN / 64, 1), 256, 0, stream>>>(
        tA, nullptr, oW2T, nullptr, ob2, feature,
        out, nullptr, nullptr, nullptr, NN, DIN, DFFN, 1);
}